// Round 8
// baseline (242.714 us; speedup 1.0000x reference)
//
#include <hip/hip_runtime.h>
#include <hip/hip_cooperative_groups.h>
#include <math.h>

namespace cg = cooperative_groups;

#define H 5
#define IN_SIZE 128
#define OUT_SIZE 128
#define BATCH 2048

// ---- Chebyshev compression parameters ----
#define DEG 20
#define NC (DEG + 1)          // 21 coefficients
#define KNOD 32               // fit nodes
#define ARANGE 5.5f
#define AINV (1.0f / 5.5f)

// ---- MFMA tier workspace: Ct in GEMM-ready padded layout ----
// Ct[o][i*22 + k], k<21 = coeff, k==21 = 0 (pad). Per-o row = 2816 u16.
#define KROW 2816
#define WS_MFMA ((size_t)OUT_SIZE * KROW * 2)          // 720,896 B

// ---- middle tier (round-4 verified path) ----
#define CPAD 2816
#define WS_F32 ((size_t)IN_SIZE * CPAD * sizeof(float))  // 1,441,792

#define LDB 360

typedef __attribute__((ext_vector_type(8))) short bf16x8;   // 8 bf16 = 4 VGPR
typedef __attribute__((ext_vector_type(4))) float f32x4;

__device__ __forceinline__ unsigned short f2bf(float f) {   // RNE f32->bf16
    unsigned int u = __float_as_uint(f);
    return (unsigned short)((u + 0x7FFF + ((u >> 16) & 1)) >> 16);
}
__device__ __forceinline__ unsigned int packbf(float lo, float hi) {
    return (unsigned int)f2bf(lo) | ((unsigned int)f2bf(hi) << 16);
}

// =====================================================================
// Tier-1 SINGLE-DISPATCH cooperative kernel.
// Grid (64,2,4) = 512 blocks x 256 thr, 69 KB LDS -> exactly 2 blocks/CU
// co-resident (512 = 2 x 256 CUs) => grid.sync() is legal.
// Phase 1: each block fits 32 nets (4 rounds x 8 nets x 32 nodes; math
//   identical to the verified fit kernel) -> Ct[o][i*22+k], and zeroes
//   its 512-float slice of out.
// threadfence + grid.sync + threadfence: agent-scope release/acquire so
//   Ct / zeroed out are visible across XCDs (non-coherent L2s, G16).
// Phase 2: round-7 verified GEMM body (2 K-slices, atomic epilogue).
// =====================================================================
union SharedU {
    struct { unsigned short Bs[64 * LDB]; unsigned short As[32 * LDB]; } g;  // 69120 B
    struct { float sw[32 * 46]; float ybuf[8][KNOD]; } f;                    // 6912 B
};

__global__ __launch_bounds__(256, 2) void fused_all_kernel(
    const float* __restrict__ x,
    const float* __restrict__ W0, const float* __restrict__ b0,
    const float* __restrict__ W1, const float* __restrict__ b1,
    const float* __restrict__ W2, const float* __restrict__ b2,
    unsigned short* ct, float* out)
{
    __shared__ SharedU shm;
    const int tid = threadIdx.x;
    const int blk = blockIdx.x + 64 * blockIdx.y + 128 * blockIdx.z;  // 0..511

    // ================= Phase 1: fit 32 nets + zero out slice =================
    {
        // zero out: 512 blocks x 512 floats (128 float4 per block)
        if (tid < 128) {
            float4 z = make_float4(0.f, 0.f, 0.f, 0.f);
            *(float4*)(out + (size_t)blk * 512 + tid * 4) = z;
        }

        const int n0 = blk * 32;
        // stage 32 nets' weights per-net-contiguous: wp = sw + nl*46
        //  [0..4]=w0 [5..9]=b0 [10..34]=w1 [35..39]=b1 [40..44]=w2 [45]=b2
        for (int idx = tid; idx < 32 * 46; idx += 256) {
            const int nl = idx / 46, f = idx - nl * 46;
            const int n = n0 + nl;
            float v;
            if      (f <  5) v = W0[n * 5  + f];
            else if (f < 10) v = b0[n * 5  + (f - 5)];
            else if (f < 35) v = W1[n * 25 + (f - 10)];
            else if (f < 40) v = b1[n * 5  + (f - 35)];
            else if (f < 45) v = W2[n * 5  + (f - 40)];
            else             v = b2[n];
            shm.f.sw[idx] = v;
        }
        __syncthreads();

        const int net8 = tid >> 5;           // 0..7
        const int k    = tid & 31;           // node / coeff index
        const float theta = (k + 0.5f) * (float)(M_PI / KNOD);
        const float xv = ARANGE * __cosf(theta);

        #pragma unroll 1
        for (int q = 0; q < 4; ++q) {
            const int nl = q * 8 + net8;
            const float* wp = shm.f.sw + nl * 46;

            float h1[H];
            #pragma unroll
            for (int j = 0; j < H; ++j) {
                float p = fmaf(wp[j], xv, wp[5 + j]);
                h1[j] = p / (1.0f + __expf(-p));
            }
            float h2[H];
            #pragma unroll
            for (int kk = 0; kk < H; ++kk) {
                float p = wp[35 + kk];
                #pragma unroll
                for (int j = 0; j < H; ++j)
                    p = fmaf(wp[10 + kk * 5 + j], h1[j], p);
                h2[kk] = p / (1.0f + __expf(-p));
            }
            float y = wp[45];
            #pragma unroll
            for (int kk = 0; kk < H; ++kk)
                y = fmaf(wp[40 + kk], h2[kk], y);

            __syncthreads();                 // prev round's DCT readers done
            shm.f.ybuf[net8][k] = y;
            __syncthreads();

            const int n = n0 + nl;
            const int i = n >> 7;            // n = i*128 + o
            const int o = n & 127;
            if (k < NC) {
                float s = 0.0f;
                for (int kk = 0; kk < KNOD; ++kk) {
                    float ang = (float)k * ((kk + 0.5f) * (float)(M_PI / KNOD));
                    s += shm.f.ybuf[net8][kk] * __cosf(ang);
                }
                s *= (k == 0) ? (1.0f / KNOD) : (2.0f / KNOD);
                ct[(size_t)o * KROW + i * 22 + k] = f2bf(s);
            } else if (k == NC) {
                ct[(size_t)o * KROW + i * 22 + NC] = 0;   // pad position
            }
        }
    }

    // ---- grid-wide barrier with explicit agent-scope fences (cross-XCD) ----
    __threadfence();                 // release: write back Ct / out zeros
    cg::this_grid().sync();
    __threadfence();                 // acquire: invalidate stale L2 copies

    // ================= Phase 2: fused feat + GEMM (round-7 verified) =========
    {
        const int mt = blockIdx.x;          // 0..63  (32 batch rows)
        const int oh = blockIdx.y;          // 0..1   (64 o-cols)
        const int bb = mt * 32;

        const int lane = tid & 63, w = tid >> 6;
        const int wm = w >> 1, wn = w & 1;            // 2m x 2n wave grid
        const int l16 = lane & 15, lg = lane >> 4;

        unsigned short* Bs = shm.g.Bs;
        unsigned short* As = shm.g.As;

        const unsigned short* aptr  = As + (wm * 16 + l16) * LDB + lg * 8;
        const unsigned short* bptr0 = Bs + (wn * 32 + l16) * LDB + lg * 8;
        const unsigned short* bptr1 = bptr0 + 16 * LDB;

        f32x4 acc0 = {0.f, 0.f, 0.f, 0.f};
        f32x4 acc1 = {0.f, 0.f, 0.f, 0.f};

        #pragma unroll
        for (int s = 0; s < 2; ++s) {
            const int kz = blockIdx.z * 2 + s;
            const int kbase = kz * 352;     // u16 offset within an o-row
            const int i0 = kz * 16;

            __syncthreads();                // prev phase/slice readers done

            // ---- stage B-slice: thread = (o = tid>>2, quarter c = tid&3) ----
            {
                const int o = tid >> 2, c = tid & 3;
                const unsigned short* src = ct + (size_t)(oh * 64 + o) * KROW + kbase;
                unsigned short* drow = Bs + o * LDB;
                #pragma unroll
                for (int j = 0; j < 11; ++j) {
                    const int kloc = c * 88 + j * 8;        // covers 0..351 exactly
                    *(float4*)(drow + kloc) = *(const float4*)(src + kloc);
                }
            }

            // ---- features -> LDS A-tile: thread = (b = tid&31, iloc = tid>>5, +8) ----
            {
                const int b  = tid & 31;
                const int s0 = tid >> 5;
                unsigned int* A32 = (unsigned int*)(As + b * LDB);
                #pragma unroll
                for (int q = 0; q < 2; ++q) {
                    const int iloc = s0 + q * 8;
                    const float t = x[(size_t)(bb + b) * IN_SIZE + i0 + iloc] * AINV;
                    float Tv[NC];
                    Tv[0] = 1.0f;
                    Tv[1] = t;
                    const float t2 = t + t;
                    #pragma unroll
                    for (int k = 2; k < NC; ++k)
                        Tv[k] = fmaf(t2, Tv[k - 1], -Tv[k - 2]);
                    unsigned int* dst = A32 + iloc * 11;    // iloc*22 u16 = iloc*11 u32
                    #pragma unroll
                    for (int j = 0; j < 10; ++j)
                        dst[j] = packbf(Tv[2 * j], Tv[2 * j + 1]);
                    dst[10] = packbf(Tv[20], 0.0f);         // (T20, pad 0)
                }
            }
            __syncthreads();

            // ---- 11 ksteps x 2 MFMA, accumulate across both slices ----
            #pragma unroll
            for (int ks = 0; ks < 11; ++ks) {
                bf16x8 a   = *(const bf16x8*)(aptr  + ks * 32);
                bf16x8 b0v = *(const bf16x8*)(bptr0 + ks * 32);
                bf16x8 b1v = *(const bf16x8*)(bptr1 + ks * 32);
                acc0 = __builtin_amdgcn_mfma_f32_16x16x32_bf16(a, b0v, acc0, 0, 0, 0);
                acc1 = __builtin_amdgcn_mfma_f32_16x16x32_bf16(a, b1v, acc1, 0, 0, 0);
            }
        }

        // ---- epilogue: 4 kz2-blocks accumulate per out element ----
        const int orow = bb + wm * 16 + lg * 4;
        const int ocol = oh * 64 + wn * 32 + l16;
        #pragma unroll
        for (int r = 0; r < 4; ++r) {
            atomicAdd(&out[(size_t)(orow + r) * OUT_SIZE + ocol],      acc0[r]);
            atomicAdd(&out[(size_t)(orow + r) * OUT_SIZE + ocol + 16], acc1[r]);
        }
    }
}

// =====================================================================
// Round-7 verified 2-dispatch pair (fallback if cooperative launch fails)
// =====================================================================
__global__ __launch_bounds__(256, 4) void fit_bf16_kernel(
    const float* __restrict__ W0, const float* __restrict__ b0,
    const float* __restrict__ W1, const float* __restrict__ b1,
    const float* __restrict__ W2, const float* __restrict__ b2,
    unsigned short* __restrict__ ct, float* __restrict__ out)
{
    __shared__ float sw[368];
    __shared__ float ybuf[8][KNOD];
    const int tid = threadIdx.x;
    const int n0  = blockIdx.x * 8;

    if (tid < 128)
        out[(size_t)blockIdx.x * 128 + tid] = 0.0f;

    for (int idx = tid; idx < 368; idx += 256) {
        float v;
        if      (idx <  40) v = W0[n0 * 5  + idx];
        else if (idx <  80) v = b0[n0 * 5  + (idx - 40)];
        else if (idx < 280) v = W1[n0 * 25 + (idx - 80)];
        else if (idx < 320) v = b1[n0 * 5  + (idx - 280)];
        else if (idx < 360) v = W2[n0 * 5  + (idx - 320)];
        else                v = b2[n0 + (idx - 360)];
        sw[idx] = v;
    }
    __syncthreads();

    const int net8 = tid >> 5;
    const int k    = tid & 31;
    const int n    = n0 + net8;
    const float* w0r = sw + net8 * 5;
    const float* b0r = sw + 40  + net8 * 5;
    const float* w1r = sw + 80  + net8 * 25;
    const float* b1r = sw + 280 + net8 * 5;
    const float* w2r = sw + 320 + net8 * 5;
    const float  b2s = sw[360 + net8];

    const float theta = (k + 0.5f) * (float)(M_PI / KNOD);
    const float xv = ARANGE * __cosf(theta);

    float h1[H];
    #pragma unroll
    for (int j = 0; j < H; ++j) {
        float p = fmaf(w0r[j], xv, b0r[j]);
        h1[j] = p / (1.0f + __expf(-p));
    }
    float h2[H];
    #pragma unroll
    for (int kk = 0; kk < H; ++kk) {
        float p = b1r[kk];
        #pragma unroll
        for (int j = 0; j < H; ++j)
            p = fmaf(w1r[kk * H + j], h1[j], p);
        h2[kk] = p / (1.0f + __expf(-p));
    }
    float y = b2s;
    #pragma unroll
    for (int kk = 0; kk < H; ++kk)
        y = fmaf(w2r[kk], h2[kk], y);

    ybuf[net8][k] = y;
    __syncthreads();

    const int i = n >> 7;
    const int o = n & 127;
    if (k < NC) {
        float s = 0.0f;
        for (int kk = 0; kk < KNOD; ++kk) {
            float ang = (float)k * ((kk + 0.5f) * (float)(M_PI / KNOD));
            s += ybuf[net8][kk] * __cosf(ang);
        }
        s *= (k == 0) ? (1.0f / KNOD) : (2.0f / KNOD);
        ct[(size_t)o * KROW + i * 22 + k] = f2bf(s);
    } else if (k == NC) {
        ct[(size_t)o * KROW + i * 22 + NC] = 0;
    }
}

__global__ __launch_bounds__(256, 2) void gemm_fused_kernel(
    const float* __restrict__ x,
    const unsigned short* __restrict__ Ct,
    float* __restrict__ out)
{
    __shared__ __align__(16) unsigned short Bs[64 * LDB];
    __shared__ __align__(16) unsigned short As[32 * LDB];

    const int tid = threadIdx.x;
    const int mt = blockIdx.x;
    const int oh = blockIdx.y;
    const int bb = mt * 32;

    const int lane = tid & 63, w = tid >> 6;
    const int wm = w >> 1, wn = w & 1;
    const int l16 = lane & 15, lg = lane >> 4;

    const unsigned short* aptr  = As + (wm * 16 + l16) * LDB + lg * 8;
    const unsigned short* bptr0 = Bs + (wn * 32 + l16) * LDB + lg * 8;
    const unsigned short* bptr1 = bptr0 + 16 * LDB;

    f32x4 acc0 = {0.f, 0.f, 0.f, 0.f};
    f32x4 acc1 = {0.f, 0.f, 0.f, 0.f};

    #pragma unroll
    for (int s = 0; s < 2; ++s) {
        const int kz = blockIdx.z * 2 + s;
        const int kbase = kz * 352;
        const int i0 = kz * 16;

        if (s) __syncthreads();

        {
            const int o = tid >> 2, c = tid & 3;
            const unsigned short* src = Ct + (size_t)(oh * 64 + o) * KROW + kbase;
            unsigned short* drow = Bs + o * LDB;
            #pragma unroll
            for (int j = 0; j < 11; ++j) {
                const int kloc = c * 88 + j * 8;
                *(float4*)(drow + kloc) = *(const float4*)(src + kloc);
            }
        }

        {
            const int b  = tid & 31;
            const int s0 = tid >> 5;
            unsigned int* A32 = (unsigned int*)(As + b * LDB);
            #pragma unroll
            for (int q = 0; q < 2; ++q) {
                const int iloc = s0 + q * 8;
                const float t = x[(size_t)(bb + b) * IN_SIZE + i0 + iloc] * AINV;
                float Tv[NC];
                Tv[0] = 1.0f;
                Tv[1] = t;
                const float t2 = t + t;
                #pragma unroll
                for (int k = 2; k < NC; ++k)
                    Tv[k] = fmaf(t2, Tv[k - 1], -Tv[k - 2]);
                unsigned int* dst = A32 + iloc * 11;
                #pragma unroll
                for (int j = 0; j < 10; ++j)
                    dst[j] = packbf(Tv[2 * j], Tv[2 * j + 1]);
                dst[10] = packbf(Tv[20], 0.0f);
            }
        }
        __syncthreads();

        #pragma unroll
        for (int ks = 0; ks < 11; ++ks) {
            bf16x8 a   = *(const bf16x8*)(aptr  + ks * 32);
            bf16x8 b0v = *(const bf16x8*)(bptr0 + ks * 32);
            bf16x8 b1v = *(const bf16x8*)(bptr1 + ks * 32);
            acc0 = __builtin_amdgcn_mfma_f32_16x16x32_bf16(a, b0v, acc0, 0, 0, 0);
            acc1 = __builtin_amdgcn_mfma_f32_16x16x32_bf16(a, b1v, acc1, 0, 0, 0);
        }
    }

    const int orow = bb + wm * 16 + lg * 4;
    const int ocol = oh * 64 + wn * 32 + l16;
    #pragma unroll
    for (int r = 0; r < 4; ++r) {
        atomicAdd(&out[(size_t)(orow + r) * OUT_SIZE + ocol],      acc0[r]);
        atomicAdd(&out[(size_t)(orow + r) * OUT_SIZE + ocol + 16], acc1[r]);
    }
}

// =====================================================================
// Tier-2: round-4 verified fp32 path (fit f32 + eval), 49 us eval.
// =====================================================================
__global__ __launch_bounds__(256, 4) void fit_kernel(
    const float* __restrict__ W0, const float* __restrict__ b0,
    const float* __restrict__ W1, const float* __restrict__ b1,
    const float* __restrict__ W2, const float* __restrict__ b2,
    float* __restrict__ coef)
{
    __shared__ float sw[368];
    __shared__ float ybuf[8][KNOD];
    const int tid = threadIdx.x;
    const int n0  = blockIdx.x * 8;

    for (int idx = tid; idx < 368; idx += 256) {
        float v;
        if      (idx <  40) v = W0[n0 * 5  + idx];
        else if (idx <  80) v = b0[n0 * 5  + (idx - 40)];
        else if (idx < 280) v = W1[n0 * 25 + (idx - 80)];
        else if (idx < 320) v = b1[n0 * 5  + (idx - 280)];
        else if (idx < 360) v = W2[n0 * 5  + (idx - 320)];
        else                v = b2[n0 + (idx - 360)];
        sw[idx] = v;
    }
    __syncthreads();

    const int net8 = tid >> 5;
    const int k    = tid & 31;
    const int n    = n0 + net8;
    const float* w0r = sw + net8 * 5;
    const float* b0r = sw + 40  + net8 * 5;
    const float* w1r = sw + 80  + net8 * 25;
    const float* b1r = sw + 280 + net8 * 5;
    const float* w2r = sw + 320 + net8 * 5;
    const float  b2s = sw[360 + net8];

    const float theta = (k + 0.5f) * (float)(M_PI / KNOD);
    const float xv = ARANGE * __cosf(theta);

    float h1[H];
    #pragma unroll
    for (int j = 0; j < H; ++j) {
        float p = fmaf(w0r[j], xv, b0r[j]);
        h1[j] = p / (1.0f + __expf(-p));
    }
    float h2[H];
    #pragma unroll
    for (int kk = 0; kk < H; ++kk) {
        float p = b1r[kk];
        #pragma unroll
        for (int j = 0; j < H; ++j)
            p = fmaf(w1r[kk * H + j], h1[j], p);
        h2[kk] = p / (1.0f + __expf(-p));
    }
    float y = b2s;
    #pragma unroll
    for (int kk = 0; kk < H; ++kk)
        y = fmaf(w2r[kk], h2[kk], y);

    ybuf[net8][k] = y;
    __syncthreads();

    const int i = n >> 7;
    const int o = n & 127;
    if (k < NC) {
        float s = 0.0f;
        for (int kk = 0; kk < KNOD; ++kk) {
            float ang = (float)k * ((kk + 0.5f) * (float)(M_PI / KNOD));
            s += ybuf[net8][kk] * __cosf(ang);
        }
        s *= (k == 0) ? (1.0f / KNOD) : (2.0f / KNOD);
        coef[(size_t)i * CPAD + k * OUT_SIZE + o] = s;
    } else if (k == NC) {
        coef[(size_t)i * CPAD + NC * OUT_SIZE + o] = 0.0f;
    }
}

__global__ __launch_bounds__(256, 2) void eval_kernel(
    const float* __restrict__ x, const float* __restrict__ coef,
    float* __restrict__ out)
{
    __shared__ __align__(16) float A[16 * NC * 32];
    __shared__ __align__(16) float Bb[2][CPAD];

    const int tid = threadIdx.x;
    const int bb  = blockIdx.x * 32;
    const int i0  = blockIdx.y * 16;

    {
        const int b  = tid & 31;
        const int s0 = tid >> 5;
        #pragma unroll
        for (int q = 0; q < 2; ++q) {
            const int isub = s0 + q * 8;
            float t  = x[(size_t)(bb + b) * IN_SIZE + i0 + isub] * AINV;
            float t2 = t + t;
            float* ap = A + (isub * NC) * 32 + b;
            float Tm = 1.0f, Tc = t;
            ap[0]  = 1.0f;
            ap[32] = t;
            #pragma unroll
            for (int k = 2; k < NC; ++k) {
                float Tn = fmaf(t2, Tc, -Tm);
                Tm = Tc; Tc = Tn;
                ap[k * 32] = Tn;
            }
        }
    }

    float r[11];
    {
        const float* cb = coef + (size_t)i0 * CPAD;
        #pragma unroll
        for (int j = 0; j < 11; ++j) r[j] = cb[tid + 256 * j];
        #pragma unroll
        for (int j = 0; j < 11; ++j) Bb[0][tid + 256 * j] = r[j];
    }
    __syncthreads();

    const int w  = tid >> 6;
    const int ty = (tid >> 3) & 7;
    const int tx = tid & 7;
    const int rb = ty * 4;
    const int ob = w * 32 + tx * 4;

    float acc[4][4] = {};

    #pragma unroll 1
    for (int isub = 0; isub < 16; ++isub) {
        const int cur = isub & 1;
        if (isub + 1 < 16) {
            const float* cb = coef + (size_t)(i0 + isub + 1) * CPAD;
            #pragma unroll
            for (int j = 0; j < 11; ++j) r[j] = cb[tid + 256 * j];
        }
        const float* Ab = A + (isub * NC) * 32;
        const float* Bp = Bb[cur];
        #pragma unroll
        for (int k = 0; k < NC; ++k) {
            float4 a4 = *(const float4*)(Ab + k * 32 + rb);
            float4 b4 = *(const float4*)(Bp + k * OUT_SIZE + ob);
            float av[4] = {a4.x, a4.y, a4.z, a4.w};
            float bv[4] = {b4.x, b4.y, b4.z, b4.w};
            #pragma unroll
            for (int rr = 0; rr < 4; ++rr)
                #pragma unroll
                for (int cc = 0; cc < 4; ++cc)
                    acc[rr][cc] = fmaf(av[rr], bv[cc], acc[rr][cc]);
        }
        if (isub + 1 < 16) {
            float* Bn = Bb[cur ^ 1];
            #pragma unroll
            for (int j = 0; j < 11; ++j) Bn[tid + 256 * j] = r[j];
        }
        __syncthreads();
    }

    #pragma unroll
    for (int rr = 0; rr < 4; ++rr) {
        float* orow = out + (size_t)(bb + rb + rr) * OUT_SIZE + ob;
        #pragma unroll
        for (int cc = 0; cc < 4; ++cc)
            atomicAdd(&orow[cc], acc[rr][cc]);
    }
}

// =====================================================================
// Tier-3 fallback (no workspace): verified 152 us direct kernel.
// =====================================================================
#define ICHUNK 64
#define WSTRIDE 52

__device__ __forceinline__ float silu9(float p) {
    const float c3 = -0.33333333333333f;
    const float c5 =  0.13333333333333f;
    const float c7 = -0.05396825396825f;
    const float c9 =  0.02186948853616f;
    float u  = 0.5f * p;
    float uc = fminf(fmaxf(u, -1.25f), 1.25f);
    float t  = uc * uc;
    float g  = fmaf(t, c9, c7);
    g = fmaf(t, g, c5);
    g = fmaf(t, g, c3);
    g = fmaf(t, g, 1.0f);
    return fmaf(u, uc * g, u);
}
__device__ __forceinline__ float silu5(float p) {
    const float c3 = -0.33333333333333f;
    const float c5 =  0.13333333333333f;
    float u = 0.5f * p;
    float t = u * u;
    float g = fmaf(t, c5, c3);
    g = fmaf(t, g, 1.0f);
    return fmaf(u, u * g, u);
}

__global__ __launch_bounds__(256, 8) void mlpkan_fallback(
    const float* __restrict__ x,
    const float* __restrict__ W0, const float* __restrict__ b0,
    const float* __restrict__ W1, const float* __restrict__ b1,
    const float* __restrict__ W2, const float* __restrict__ b2,
    float* __restrict__ out)
{
    __shared__ float w[ICHUNK * WSTRIDE];
    const int o  = blockIdx.x;
    const int i0 = blockIdx.z * ICHUNK;

    for (int idx = threadIdx.x; idx < ICHUNK * WSTRIDE; idx += 256) {
        int il = idx / WSTRIDE;
        int f  = idx - il * WSTRIDE;
        int n  = (i0 + il) * OUT_SIZE + o;
        float v = 0.0f;
        if (f < 5)                   v = W0[n * 5 + f];
        else if (f < 10)             v = b0[n * 5 + (f - 5)];
        else if (f >= 12 && f < 37)  v = W1[n * 25 + (f - 12)];
        else if (f >= 37 && f < 42)  v = b1[n * 5 + (f - 37)];
        else if (f >= 44 && f < 49)  v = W2[n * 5 + (f - 44)];
        else if (f == 49)            v = b2[n];
        w[idx] = v;
    }
    __syncthreads();

    const int b = blockIdx.y * 256 + threadIdx.x;
    const float* xrow = x + b * IN_SIZE + i0;
    float acc = 0.0f;

    #pragma unroll 1
    for (int i = 0; i < ICHUNK; i += 4) {
        float4 xv = *(const float4*)(xrow + i);
        float xs[4] = {xv.x, xv.y, xv.z, xv.w};
        #pragma unroll
        for (int ii = 0; ii < 4; ++ii) {
            const float4* q = (const float4*)(w + (i + ii) * WSTRIDE);
            const float xi = xs[ii];
            float g0[12];
            #pragma unroll
            for (int t = 0; t < 3; ++t) *(float4*)(g0 + 4 * t) = q[t];
            float h1[H];
            #pragma unroll
            for (int j = 0; j < H; ++j)
                h1[j] = silu9(fmaf(g0[j], xi, g0[5 + j]));
            float g1[32];
            #pragma unroll
            for (int t = 0; t < 8; ++t) *(float4*)(g1 + 4 * t) = q[3 + t];
            float h2[H];
            #pragma unroll
            for (int k = 0; k < H; ++k) {
                float p = g1[25 + k];
                #pragma unroll
                for (int j = 0; j < H; ++j)
                    p = fmaf(g1[5 * k + j], h1[j], p);
                h2[k] = silu5(p);
            }
            float g2[8];
            #pragma unroll
            for (int t = 0; t < 2; ++t) *(float4*)(g2 + 4 * t) = q[11 + t];
            float y = g2[5];
            #pragma unroll
            for (int k = 0; k < H; ++k)
                y = fmaf(g2[k], h2[k], y);
            acc += y;
        }
    }
    atomicAdd(&out[b * OUT_SIZE + o], acc);
}

extern "C" void kernel_launch(void* const* d_in, const int* in_sizes, int n_in,
                              void* d_out, int out_size, void* d_ws, size_t ws_size,
                              hipStream_t stream) {
    const float* x  = (const float*)d_in[0];
    const float* W0 = (const float*)d_in[1];
    const float* b0 = (const float*)d_in[2];
    const float* W1 = (const float*)d_in[3];
    const float* b1 = (const float*)d_in[4];
    const float* W2 = (const float*)d_in[5];
    const float* b2 = (const float*)d_in[6];
    float* out = (float*)d_out;

    if (ws_size >= WS_MFMA && d_ws != nullptr) {
        unsigned short* Ct = (unsigned short*)d_ws;
        // ONE cooperative dispatch: fit + out-zero + grid.sync + feat/GEMM
        dim3 grid(BATCH / 32, 2, 4);   // (64,2,4) = 512 blocks = 2/CU
        dim3 block(256);
        void* args[] = {(void*)&x, (void*)&W0, (void*)&b0, (void*)&W1, (void*)&b1,
                        (void*)&W2, (void*)&b2, (void*)&Ct, (void*)&out};
        hipError_t err = hipLaunchCooperativeKernel(
            (const void*)fused_all_kernel, grid, block, args, 0, stream);
        if (err != hipSuccess) {
            // fallback: round-7 verified 2-dispatch path
            fit_bf16_kernel<<<dim3(IN_SIZE * OUT_SIZE / 8), dim3(256), 0, stream>>>(
                W0, b0, W1, b1, W2, b2, Ct, out);
            gemm_fused_kernel<<<dim3(BATCH / 32, 2, 4), dim3(256), 0, stream>>>(
                x, Ct, out);
        }
    } else if (ws_size >= WS_F32 && d_ws != nullptr) {
        float* coef = (float*)d_ws;
        hipMemsetAsync(out, 0, (size_t)out_size * sizeof(float), stream);
        fit_kernel<<<dim3(IN_SIZE * OUT_SIZE / 8), dim3(256), 0, stream>>>(
            W0, b0, W1, b1, W2, b2, coef);
        eval_kernel<<<dim3(BATCH / 32, IN_SIZE / 16), dim3(256), 0, stream>>>(
            x, coef, out);
    } else {
        hipMemsetAsync(out, 0, (size_t)out_size * sizeof(float), stream);
        dim3 grid(OUT_SIZE, BATCH / 256, IN_SIZE / ICHUNK);
        mlpkan_fallback<<<grid, dim3(256), 0, stream>>>(x, W0, b0, W1, b1, W2, b2, out);
    }
}

// Round 9
// 81.338 us; speedup vs baseline: 2.9840x; 2.9840x over previous
//
#include <hip/hip_runtime.h>
#include <math.h>

#define H 5
#define IN_SIZE 128
#define OUT_SIZE 128
#define BATCH 2048

// ---- Chebyshev compression parameters ----
#define DEG 20
#define NC (DEG + 1)          // 21 coefficients
#define KNOD 32               // fit nodes
#define ARANGE 5.5f
#define AINV (1.0f / 5.5f)

// ---- MFMA tier workspace: Ct in GEMM-ready padded layout ----
// Ct[o][i*22 + k], k<21 = coeff, k==21 = 0 (pad). Per-o row = 128*22 =
// 2816 u16. K-slice of 16 i = exactly 352 u16 -> predicate-free float4
// staging, and A-rows hit even u16 offsets (22 even) -> packed u32
// feature stores. A/B pads align so padded products are exactly 0.
//
// NOTE (round-8 lesson): do NOT fuse fit+gemm via cooperative launch.
// cg::this_grid().sync() at 512 blocks on MI355X costs ~145 us (spin on
// a device-scope atomic across 8 non-coherent XCD L2s) vs the ~5 us
// dispatch gap it replaces. Two dispatches is the optimum here.
#define KROW 2816                                      // u16 per o-row
#define WS_MFMA ((size_t)OUT_SIZE * KROW * 2)          // 720,896 B

// ---- middle tier (round-4 verified path) ----
#define CPAD 2816
#define WS_F32 ((size_t)IN_SIZE * CPAD * sizeof(float))  // 1,441,792

typedef __attribute__((ext_vector_type(8))) short bf16x8;   // 8 bf16 = 4 VGPR
typedef __attribute__((ext_vector_type(4))) float f32x4;

__device__ __forceinline__ unsigned short f2bf(float f) {   // RNE f32->bf16
    unsigned int u = __float_as_uint(f);
    return (unsigned short)((u + 0x7FFF + ((u >> 16) & 1)) >> 16);
}
__device__ __forceinline__ unsigned int packbf(float lo, float hi) {
    return (unsigned int)f2bf(lo) | ((unsigned int)f2bf(hi) << 16);
}

// =====================================================================
// Tier-1 fit: exact silu eval at 32 Chebyshev nodes + DCT -> bf16 coeffs
// in padded layout Ct[o][i*22+k] (k==21 zeroed). Also zeroes `out`
// (2048 blocks x 128 floats) so no separate memset dispatch.
// =====================================================================
__global__ __launch_bounds__(256, 4) void fit_bf16_kernel(
    const float* __restrict__ W0, const float* __restrict__ b0,
    const float* __restrict__ W1, const float* __restrict__ b1,
    const float* __restrict__ W2, const float* __restrict__ b2,
    unsigned short* __restrict__ ct, float* __restrict__ out)
{
    __shared__ float sw[368];
    __shared__ float ybuf[8][KNOD];
    const int tid = threadIdx.x;
    const int n0  = blockIdx.x * 8;

    if (tid < 128)   // zero out: 2048 blocks x 128 = 262144 floats
        out[(size_t)blockIdx.x * 128 + tid] = 0.0f;

    for (int idx = tid; idx < 368; idx += 256) {
        float v;
        if      (idx <  40) v = W0[n0 * 5  + idx];
        else if (idx <  80) v = b0[n0 * 5  + (idx - 40)];
        else if (idx < 280) v = W1[n0 * 25 + (idx - 80)];
        else if (idx < 320) v = b1[n0 * 5  + (idx - 280)];
        else if (idx < 360) v = W2[n0 * 5  + (idx - 320)];
        else                v = b2[n0 + (idx - 360)];
        sw[idx] = v;
    }
    __syncthreads();

    const int net8 = tid >> 5;
    const int k    = tid & 31;
    const int n    = n0 + net8;
    const float* w0r = sw + net8 * 5;
    const float* b0r = sw + 40  + net8 * 5;
    const float* w1r = sw + 80  + net8 * 25;
    const float* b1r = sw + 280 + net8 * 5;
    const float* w2r = sw + 320 + net8 * 5;
    const float  b2s = sw[360 + net8];

    const float theta = (k + 0.5f) * (float)(M_PI / KNOD);
    const float xv = ARANGE * __cosf(theta);

    float h1[H];
    #pragma unroll
    for (int j = 0; j < H; ++j) {
        float p = fmaf(w0r[j], xv, b0r[j]);
        h1[j] = p / (1.0f + __expf(-p));
    }
    float h2[H];
    #pragma unroll
    for (int kk = 0; kk < H; ++kk) {
        float p = b1r[kk];
        #pragma unroll
        for (int j = 0; j < H; ++j)
            p = fmaf(w1r[kk * H + j], h1[j], p);
        h2[kk] = p / (1.0f + __expf(-p));
    }
    float y = b2s;
    #pragma unroll
    for (int kk = 0; kk < H; ++kk)
        y = fmaf(w2r[kk], h2[kk], y);

    ybuf[net8][k] = y;
    __syncthreads();

    const int i = n >> 7;            // n = i*128 + o
    const int o = n & 127;
    if (k < NC) {
        float s = 0.0f;
        for (int kk = 0; kk < KNOD; ++kk) {
            float ang = (float)k * ((kk + 0.5f) * (float)(M_PI / KNOD));
            s += ybuf[net8][kk] * __cosf(ang);
        }
        s *= (k == 0) ? (1.0f / KNOD) : (2.0f / KNOD);
        ct[(size_t)o * KROW + i * 22 + k] = f2bf(s);
    } else if (k == NC) {
        ct[(size_t)o * KROW + i * 22 + NC] = 0;   // pad position
    }
}

// =====================================================================
// Tier-1 fused GEMM: out[b,o] += sum_{i,k} T_k(x[b,i]) * Ct[o][i*22+k].
// Grid (64 mt, 2 oh, 4 kz2) = 512 blocks = exactly 2/CU co-resident.
// Each block accumulates TWO 352-K slices in registers before a single
// atomic epilogue -> atomics 4/elem. Per slice: predicate-free
// B-staging (11 float4/thread), features computed in-kernel as 11
// packed u32 LDS stores/row. MFMA mapping m89-verified.
// LDS rows stride 360 u16 = 720 B -> row-step 20 banks, <=2-way = free.
// =====================================================================
#define LDB 360

__global__ __launch_bounds__(256, 2) void gemm_fused_kernel(
    const float* __restrict__ x,
    const unsigned short* __restrict__ Ct,
    float* __restrict__ out)
{
    __shared__ __align__(16) unsigned short Bs[64 * LDB];   // 46080 B
    __shared__ __align__(16) unsigned short As[32 * LDB];   // 23040 B

    const int tid = threadIdx.x;
    const int mt = blockIdx.x;          // 0..63  (32 batch rows)
    const int oh = blockIdx.y;          // 0..1   (64 o-cols)
    const int bb = mt * 32;

    const int lane = tid & 63, w = tid >> 6;
    const int wm = w >> 1, wn = w & 1;            // 2m x 2n wave grid
    const int l16 = lane & 15, lg = lane >> 4;

    const unsigned short* aptr  = As + (wm * 16 + l16) * LDB + lg * 8;
    const unsigned short* bptr0 = Bs + (wn * 32 + l16) * LDB + lg * 8;
    const unsigned short* bptr1 = bptr0 + 16 * LDB;

    f32x4 acc0 = {0.f, 0.f, 0.f, 0.f};
    f32x4 acc1 = {0.f, 0.f, 0.f, 0.f};

    #pragma unroll
    for (int s = 0; s < 2; ++s) {
        const int kz = blockIdx.z * 2 + s;
        const int kbase = kz * 352;     // u16 offset within an o-row
        const int i0 = kz * 16;

        if (s) __syncthreads();         // all waves done reading prev slice

        // ---- stage B-slice: thread = (o = tid>>2, quarter c = tid&3) ----
        {
            const int o = tid >> 2, c = tid & 3;
            const unsigned short* src = Ct + (size_t)(oh * 64 + o) * KROW + kbase;
            unsigned short* drow = Bs + o * LDB;
            #pragma unroll
            for (int j = 0; j < 11; ++j) {
                const int kloc = c * 88 + j * 8;        // covers 0..351 exactly
                *(float4*)(drow + kloc) = *(const float4*)(src + kloc);
            }
        }

        // ---- features -> LDS A-tile: thread = (b = tid&31, iloc = tid>>5, +8) ----
        {
            const int b  = tid & 31;
            const int s0 = tid >> 5;
            unsigned int* A32 = (unsigned int*)(As + b * LDB);  // row base 4B-aligned
            #pragma unroll
            for (int q = 0; q < 2; ++q) {
                const int iloc = s0 + q * 8;
                const float t = x[(size_t)(bb + b) * IN_SIZE + i0 + iloc] * AINV;
                float Tv[NC];
                Tv[0] = 1.0f;
                Tv[1] = t;
                const float t2 = t + t;
                #pragma unroll
                for (int k = 2; k < NC; ++k)
                    Tv[k] = fmaf(t2, Tv[k - 1], -Tv[k - 2]);
                unsigned int* dst = A32 + iloc * 11;    // iloc*22 u16 = iloc*11 u32
                #pragma unroll
                for (int j = 0; j < 10; ++j)
                    dst[j] = packbf(Tv[2 * j], Tv[2 * j + 1]);
                dst[10] = packbf(Tv[20], 0.0f);         // (T20, pad 0)
            }
        }
        __syncthreads();

        // ---- 11 ksteps x 2 MFMA, accumulate across both slices ----
        #pragma unroll
        for (int ks = 0; ks < 11; ++ks) {
            bf16x8 a   = *(const bf16x8*)(aptr  + ks * 32);
            bf16x8 b0v = *(const bf16x8*)(bptr0 + ks * 32);
            bf16x8 b1v = *(const bf16x8*)(bptr1 + ks * 32);
            acc0 = __builtin_amdgcn_mfma_f32_16x16x32_bf16(a, b0v, acc0, 0, 0, 0);
            acc1 = __builtin_amdgcn_mfma_f32_16x16x32_bf16(a, b1v, acc1, 0, 0, 0);
        }
    }

    // ---- epilogue: 4 kz2-blocks accumulate per out element ----
    const int orow = bb + wm * 16 + lg * 4;
    const int ocol = oh * 64 + wn * 32 + l16;
    #pragma unroll
    for (int r = 0; r < 4; ++r) {
        atomicAdd(&out[(size_t)(orow + r) * OUT_SIZE + ocol],      acc0[r]);
        atomicAdd(&out[(size_t)(orow + r) * OUT_SIZE + ocol + 16], acc1[r]);
    }
}

// =====================================================================
// Tier-2: round-4 verified fp32 path (fit f32 + eval), 49 us eval.
// =====================================================================
__global__ __launch_bounds__(256, 4) void fit_kernel(
    const float* __restrict__ W0, const float* __restrict__ b0,
    const float* __restrict__ W1, const float* __restrict__ b1,
    const float* __restrict__ W2, const float* __restrict__ b2,
    float* __restrict__ coef)
{
    __shared__ float sw[368];
    __shared__ float ybuf[8][KNOD];
    const int tid = threadIdx.x;
    const int n0  = blockIdx.x * 8;

    for (int idx = tid; idx < 368; idx += 256) {
        float v;
        if      (idx <  40) v = W0[n0 * 5  + idx];
        else if (idx <  80) v = b0[n0 * 5  + (idx - 40)];
        else if (idx < 280) v = W1[n0 * 25 + (idx - 80)];
        else if (idx < 320) v = b1[n0 * 5  + (idx - 280)];
        else if (idx < 360) v = W2[n0 * 5  + (idx - 320)];
        else                v = b2[n0 + (idx - 360)];
        sw[idx] = v;
    }
    __syncthreads();

    const int net8 = tid >> 5;
    const int k    = tid & 31;
    const int n    = n0 + net8;
    const float* w0r = sw + net8 * 5;
    const float* b0r = sw + 40  + net8 * 5;
    const float* w1r = sw + 80  + net8 * 25;
    const float* b1r = sw + 280 + net8 * 5;
    const float* w2r = sw + 320 + net8 * 5;
    const float  b2s = sw[360 + net8];

    const float theta = (k + 0.5f) * (float)(M_PI / KNOD);
    const float xv = ARANGE * __cosf(theta);

    float h1[H];
    #pragma unroll
    for (int j = 0; j < H; ++j) {
        float p = fmaf(w0r[j], xv, b0r[j]);
        h1[j] = p / (1.0f + __expf(-p));
    }
    float h2[H];
    #pragma unroll
    for (int kk = 0; kk < H; ++kk) {
        float p = b1r[kk];
        #pragma unroll
        for (int j = 0; j < H; ++j)
            p = fmaf(w1r[kk * H + j], h1[j], p);
        h2[kk] = p / (1.0f + __expf(-p));
    }
    float y = b2s;
    #pragma unroll
    for (int kk = 0; kk < H; ++kk)
        y = fmaf(w2r[kk], h2[kk], y);

    ybuf[net8][k] = y;
    __syncthreads();

    const int i = n >> 7;
    const int o = n & 127;
    if (k < NC) {
        float s = 0.0f;
        for (int kk = 0; kk < KNOD; ++kk) {
            float ang = (float)k * ((kk + 0.5f) * (float)(M_PI / KNOD));
            s += ybuf[net8][kk] * __cosf(ang);
        }
        s *= (k == 0) ? (1.0f / KNOD) : (2.0f / KNOD);
        coef[(size_t)i * CPAD + k * OUT_SIZE + o] = s;
    } else if (k == NC) {
        coef[(size_t)i * CPAD + NC * OUT_SIZE + o] = 0.0f;
    }
}

__global__ __launch_bounds__(256, 2) void eval_kernel(
    const float* __restrict__ x, const float* __restrict__ coef,
    float* __restrict__ out)
{
    __shared__ __align__(16) float A[16 * NC * 32];
    __shared__ __align__(16) float Bb[2][CPAD];

    const int tid = threadIdx.x;
    const int bb  = blockIdx.x * 32;
    const int i0  = blockIdx.y * 16;

    {
        const int b  = tid & 31;
        const int s0 = tid >> 5;
        #pragma unroll
        for (int q = 0; q < 2; ++q) {
            const int isub = s0 + q * 8;
            float t  = x[(size_t)(bb + b) * IN_SIZE + i0 + isub] * AINV;
            float t2 = t + t;
            float* ap = A + (isub * NC) * 32 + b;
            float Tm = 1.0f, Tc = t;
            ap[0]  = 1.0f;
            ap[32] = t;
            #pragma unroll
            for (int k = 2; k < NC; ++k) {
                float Tn = fmaf(t2, Tc, -Tm);
                Tm = Tc; Tc = Tn;
                ap[k * 32] = Tn;
            }
        }
    }

    float r[11];
    {
        const float* cb = coef + (size_t)i0 * CPAD;
        #pragma unroll
        for (int j = 0; j < 11; ++j) r[j] = cb[tid + 256 * j];
        #pragma unroll
        for (int j = 0; j < 11; ++j) Bb[0][tid + 256 * j] = r[j];
    }
    __syncthreads();

    const int w  = tid >> 6;
    const int ty = (tid >> 3) & 7;
    const int tx = tid & 7;
    const int rb = ty * 4;
    const int ob = w * 32 + tx * 4;

    float acc[4][4] = {};

    #pragma unroll 1
    for (int isub = 0; isub < 16; ++isub) {
        const int cur = isub & 1;
        if (isub + 1 < 16) {
            const float* cb = coef + (size_t)(i0 + isub + 1) * CPAD;
            #pragma unroll
            for (int j = 0; j < 11; ++j) r[j] = cb[tid + 256 * j];
        }
        const float* Ab = A + (isub * NC) * 32;
        const float* Bp = Bb[cur];
        #pragma unroll
        for (int k = 0; k < NC; ++k) {
            float4 a4 = *(const float4*)(Ab + k * 32 + rb);
            float4 b4 = *(const float4*)(Bp + k * OUT_SIZE + ob);
            float av[4] = {a4.x, a4.y, a4.z, a4.w};
            float bv[4] = {b4.x, b4.y, b4.z, b4.w};
            #pragma unroll
            for (int rr = 0; rr < 4; ++rr)
                #pragma unroll
                for (int cc = 0; cc < 4; ++cc)
                    acc[rr][cc] = fmaf(av[rr], bv[cc], acc[rr][cc]);
        }
        if (isub + 1 < 16) {
            float* Bn = Bb[cur ^ 1];
            #pragma unroll
            for (int j = 0; j < 11; ++j) Bn[tid + 256 * j] = r[j];
        }
        __syncthreads();
    }

    #pragma unroll
    for (int rr = 0; rr < 4; ++rr) {
        float* orow = out + (size_t)(bb + rb + rr) * OUT_SIZE + ob;
        #pragma unroll
        for (int cc = 0; cc < 4; ++cc)
            atomicAdd(&orow[cc], acc[rr][cc]);
    }
}

// =====================================================================
// Tier-3 fallback (no workspace): verified 152 us direct kernel.
// =====================================================================
#define ICHUNK 64
#define WSTRIDE 52

__device__ __forceinline__ float silu9(float p) {
    const float c3 = -0.33333333333333f;
    const float c5 =  0.13333333333333f;
    const float c7 = -0.05396825396825f;
    const float c9 =  0.02186948853616f;
    float u  = 0.5f * p;
    float uc = fminf(fmaxf(u, -1.25f), 1.25f);
    float t  = uc * uc;
    float g  = fmaf(t, c9, c7);
    g = fmaf(t, g, c5);
    g = fmaf(t, g, c3);
    g = fmaf(t, g, 1.0f);
    return fmaf(u, uc * g, u);
}
__device__ __forceinline__ float silu5(float p) {
    const float c3 = -0.33333333333333f;
    const float c5 =  0.13333333333333f;
    float u = 0.5f * p;
    float t = u * u;
    float g = fmaf(t, c5, c3);
    g = fmaf(t, g, 1.0f);
    return fmaf(u, u * g, u);
}

__global__ __launch_bounds__(256, 8) void mlpkan_fallback(
    const float* __restrict__ x,
    const float* __restrict__ W0, const float* __restrict__ b0,
    const float* __restrict__ W1, const float* __restrict__ b1,
    const float* __restrict__ W2, const float* __restrict__ b2,
    float* __restrict__ out)
{
    __shared__ float w[ICHUNK * WSTRIDE];
    const int o  = blockIdx.x;
    const int i0 = blockIdx.z * ICHUNK;

    for (int idx = threadIdx.x; idx < ICHUNK * WSTRIDE; idx += 256) {
        int il = idx / WSTRIDE;
        int f  = idx - il * WSTRIDE;
        int n  = (i0 + il) * OUT_SIZE + o;
        float v = 0.0f;
        if (f < 5)                   v = W0[n * 5 + f];
        else if (f < 10)             v = b0[n * 5 + (f - 5)];
        else if (f >= 12 && f < 37)  v = W1[n * 25 + (f - 12)];
        else if (f >= 37 && f < 42)  v = b1[n * 5 + (f - 37)];
        else if (f >= 44 && f < 49)  v = W2[n * 5 + (f - 44)];
        else if (f == 49)            v = b2[n];
        w[idx] = v;
    }
    __syncthreads();

    const int b = blockIdx.y * 256 + threadIdx.x;
    const float* xrow = x + b * IN_SIZE + i0;
    float acc = 0.0f;

    #pragma unroll 1
    for (int i = 0; i < ICHUNK; i += 4) {
        float4 xv = *(const float4*)(xrow + i);
        float xs[4] = {xv.x, xv.y, xv.z, xv.w};
        #pragma unroll
        for (int ii = 0; ii < 4; ++ii) {
            const float4* q = (const float4*)(w + (i + ii) * WSTRIDE);
            const float xi = xs[ii];
            float g0[12];
            #pragma unroll
            for (int t = 0; t < 3; ++t) *(float4*)(g0 + 4 * t) = q[t];
            float h1[H];
            #pragma unroll
            for (int j = 0; j < H; ++j)
                h1[j] = silu9(fmaf(g0[j], xi, g0[5 + j]));
            float g1[32];
            #pragma unroll
            for (int t = 0; t < 8; ++t) *(float4*)(g1 + 4 * t) = q[3 + t];
            float h2[H];
            #pragma unroll
            for (int k = 0; k < H; ++k) {
                float p = g1[25 + k];
                #pragma unroll
                for (int j = 0; j < H; ++j)
                    p = fmaf(g1[5 * k + j], h1[j], p);
                h2[k] = silu5(p);
            }
            float g2[8];
            #pragma unroll
            for (int t = 0; t < 2; ++t) *(float4*)(g2 + 4 * t) = q[11 + t];
            float y = g2[5];
            #pragma unroll
            for (int k = 0; k < H; ++k)
                y = fmaf(g2[k], h2[k], y);
            acc += y;
        }
    }
    atomicAdd(&out[b * OUT_SIZE + o], acc);
}

extern "C" void kernel_launch(void* const* d_in, const int* in_sizes, int n_in,
                              void* d_out, int out_size, void* d_ws, size_t ws_size,
                              hipStream_t stream) {
    const float* x  = (const float*)d_in[0];
    const float* W0 = (const float*)d_in[1];
    const float* b0 = (const float*)d_in[2];
    const float* W1 = (const float*)d_in[3];
    const float* b1 = (const float*)d_in[4];
    const float* W2 = (const float*)d_in[5];
    const float* b2 = (const float*)d_in[6];
    float* out = (float*)d_out;

    if (ws_size >= WS_MFMA && d_ws != nullptr) {
        unsigned short* Ct = (unsigned short*)d_ws;
        // 2 dispatches: fit (also zeroes out) -> fused feat+GEMM (2 slices/block)
        fit_bf16_kernel<<<dim3(IN_SIZE * OUT_SIZE / 8), dim3(256), 0, stream>>>(
            W0, b0, W1, b1, W2, b2, Ct, out);
        gemm_fused_kernel<<<dim3(BATCH / 32, 2, 4), dim3(256), 0, stream>>>(
            x, Ct, out);
    } else if (ws_size >= WS_F32 && d_ws != nullptr) {
        float* coef = (float*)d_ws;
        hipMemsetAsync(out, 0, (size_t)out_size * sizeof(float), stream);
        fit_kernel<<<dim3(IN_SIZE * OUT_SIZE / 8), dim3(256), 0, stream>>>(
            W0, b0, W1, b1, W2, b2, coef);
        eval_kernel<<<dim3(BATCH / 32, IN_SIZE / 16), dim3(256), 0, stream>>>(
            x, coef, out);
    } else {
        hipMemsetAsync(out, 0, (size_t)out_size * sizeof(float), stream);
        dim3 grid(OUT_SIZE, BATCH / 256, IN_SIZE / ICHUNK);
        mlpkan_fallback<<<grid, dim3(256), 0, stream>>>(x, W0, b0, W1, b1, W2, b2, out);
    }
}